// Round 1
// baseline (548.301 us; speedup 1.0000x reference)
//
#include <hip/hip_runtime.h>

#define BB 16384
#define DD 256
#define EE 8
#define HH 128

// tanh via exp2-based __expf; clamped so a=inf can't produce NaN.
__device__ __forceinline__ float fast_tanh(float v){
    v = fminf(fmaxf(v, -15.0f), 15.0f);
    const float a = __expf(2.0f * v);
    return (a - 1.0f) / (a + 1.0f);
}

// One wave (64 lanes) per row. Computes 8 gate logits, top-2, renormalized
// weights, and pushes (row, w) onto per-expert compacted lists.
__global__ __launch_bounds__(256) void routing_kernel(
    const float* __restrict__ x, const float* __restrict__ Wg,
    int* __restrict__ counts, int* __restrict__ rowids, float* __restrict__ wgts)
{
    __shared__ __align__(16) float WgT[EE][DD];   // Wg transposed: [e][d], 8 KB
    const int t = threadIdx.x;
    {
        // thread t loads Wg row d=t (8 floats), scatters into transposed LDS
        const float4* g = (const float4*)(Wg + t * EE);
        const float4 a = g[0], b = g[1];
        WgT[0][t] = a.x; WgT[1][t] = a.y; WgT[2][t] = a.z; WgT[3][t] = a.w;
        WgT[4][t] = b.x; WgT[5][t] = b.y; WgT[6][t] = b.z; WgT[7][t] = b.w;
    }
    __syncthreads();

    const int lane = t & 63;
    const int row  = blockIdx.x * 4 + (t >> 6);
    const float4 xv = *(const float4*)(x + row * DD + lane * 4);

    float p[EE];
    #pragma unroll
    for (int e = 0; e < EE; e++){
        const float4 w = *(const float4*)&WgT[e][lane * 4];   // b128, conflict-free
        p[e] = xv.x * w.x + xv.y * w.y + xv.z * w.z + xv.w * w.w;
    }
    #pragma unroll
    for (int off = 32; off >= 1; off >>= 1){
        #pragma unroll
        for (int e = 0; e < EE; e++) p[e] += __shfl_down(p[e], off, 64);
    }
    if (lane == 0){
        int e0 = 0; float l0 = p[0];
        #pragma unroll
        for (int e = 1; e < EE; e++){ if (p[e] > l0){ l0 = p[e]; e0 = e; } }
        int e1 = -1; float l1 = -3.0e38f;
        #pragma unroll
        for (int e = 0; e < EE; e++){ if (e != e0 && p[e] > l1){ l1 = p[e]; e1 = e; } }
        // top-2 renormalized softmax: denominators cancel; +1e-10 is below fp32 eps
        const float tt  = __expf(l1 - l0);            // <= 1
        const float inv = 1.0f / (1.0f + tt);
        const int p0 = atomicAdd(&counts[e0], 1);
        rowids[e0 * BB + p0] = row;  wgts[e0 * BB + p0] = inv;
        const int p1 = atomicAdd(&counts[e1], 1);
        rowids[e1 * BB + p1] = row;  wgts[e1 * BB + p1] = tt * inv;
    }
}

// One block = (expert me, 64 gathered rows). 128 threads; each thread owns an
// 8-row x 8-col fp32 register tile. LDS: region1 16KB (X tile / Wp chunk),
// region2 32KB (W1 tile / core), ~48.5 KB total -> 3 blocks/CU.
__global__ __launch_bounds__(128) void expert_kernel(
    const float* __restrict__ x,
    const float* __restrict__ W1, const float* __restrict__ b1,
    const float* __restrict__ Wp, const float* __restrict__ bp,
    const float* __restrict__ mix_logit,
    const float* __restrict__ Wo, const float* __restrict__ bo,
    const int* __restrict__ counts, const int* __restrict__ rowids,
    const float* __restrict__ wgts, float* __restrict__ out)
{
    const int me    = blockIdx.y;
    const int cnt   = counts[me];
    const int start = blockIdx.x * 64;
    if (start >= cnt) return;

    __shared__ __align__(16) float reg1[64 * 64];    // 16 KB: Xs[64][64] | WpS[32][128]
    __shared__ __align__(16) float reg2[64 * 128];   // 32 KB: Ws[64][128] | coreS[64][128]
    __shared__ int   rid_s[64];
    __shared__ float w_s[64];

    float* const Xs    = reg1;   // [r][k] stride 64
    float* const WpS   = reg1;   // [k][h] stride 128 (32 rows)
    float* const Ws    = reg2;   // [k][h] stride 128
    float* const coreS = reg2;   // [r][h] stride 128

    const int t  = threadIdx.x;
    if (t < 64){
        const int idx = start + t;
        if (idx < cnt){ rid_s[t] = rowids[me * BB + idx]; w_s[t] = wgts[me * BB + idx]; }
        else          { rid_s[t] = 0;                     w_s[t] = 0.0f; }
    }
    __syncthreads();

    const int hg = t & 15;  const int h8 = hg * 8;
    const int rg = t >> 4;  const int r8 = rg * 8;

    // ---- phase 1: core = relu(x @ W1[e] + b1[e]) ----
    float acc[8][8];
    #pragma unroll
    for (int j = 0; j < 8; j++){
        const float bj = b1[me * HH + h8 + j];
        #pragma unroll
        for (int i = 0; i < 8; i++) acc[i][j] = bj;
    }

    for (int kc = 0; kc < DD; kc += 64){
        __syncthreads();   // previous tile fully consumed
        #pragma unroll
        for (int j = 0; j < 8; j++){           // X tile: 64 rows x 64 k
            const int q = t + 128 * j;
            const int r = q >> 4, kp = (q & 15) * 4;
            *(float4*)&Xs[r * 64 + kp] = *(const float4*)(x + rid_s[r] * DD + kc + kp);
        }
        #pragma unroll
        for (int j = 0; j < 16; j++){          // W1 tile: 64 k x 128 h
            const int q = t + 128 * j;
            const int k = q >> 5, hp = (q & 31) * 4;
            *(float4*)&Ws[k * HH + hp] = *(const float4*)(W1 + (me * DD + kc + k) * HH + hp);
        }
        __syncthreads();
        #pragma unroll
        for (int k0 = 0; k0 < 64; k0 += 4){
            float4 xr[8];
            #pragma unroll
            for (int i = 0; i < 8; i++) xr[i] = *(const float4*)&Xs[(r8 + i) * 64 + k0];
            #pragma unroll
            for (int kk = 0; kk < 4; kk++){
                const float4 wa = *(const float4*)&Ws[(k0 + kk) * HH + h8];
                const float4 wb = *(const float4*)&Ws[(k0 + kk) * HH + h8 + 4];
                #pragma unroll
                for (int i = 0; i < 8; i++){
                    const float xvv = (kk == 0) ? xr[i].x : (kk == 1) ? xr[i].y : (kk == 2) ? xr[i].z : xr[i].w;
                    acc[i][0] = fmaf(xvv, wa.x, acc[i][0]);
                    acc[i][1] = fmaf(xvv, wa.y, acc[i][1]);
                    acc[i][2] = fmaf(xvv, wa.z, acc[i][2]);
                    acc[i][3] = fmaf(xvv, wa.w, acc[i][3]);
                    acc[i][4] = fmaf(xvv, wb.x, acc[i][4]);
                    acc[i][5] = fmaf(xvv, wb.y, acc[i][5]);
                    acc[i][6] = fmaf(xvv, wb.z, acc[i][6]);
                    acc[i][7] = fmaf(xvv, wb.w, acc[i][7]);
                }
            }
        }
    }

    // epilogue constants
    const float mv  = 1.0f / (1.0f + __expf(-mix_logit[me]));  // sigmoid
    const float om  = 1.0f - mv;
    const float bov = bo[me];
    float wo[8];
    #pragma unroll
    for (int j = 0; j < 8; j++) wo[j] = Wo[me * HH + h8 + j];

    __syncthreads();   // all Ws/Xs reads done -> safe to overlay

    // relu, write core to LDS, and fold core's output contribution now so acc dies
    float pc[8];
    #pragma unroll
    for (int i = 0; i < 8; i++){
        float s = 0.0f;
        #pragma unroll
        for (int j = 0; j < 8; j++){
            acc[i][j] = fmaxf(acc[i][j], 0.0f);
            s = fmaf(acc[i][j], wo[j], s);
        }
        pc[i] = s;
        *(float4*)&coreS[(r8 + i) * HH + h8]     = make_float4(acc[i][0], acc[i][1], acc[i][2], acc[i][3]);
        *(float4*)&coreS[(r8 + i) * HH + h8 + 4] = make_float4(acc[i][4], acc[i][5], acc[i][6], acc[i][7]);
    }

    // ---- phase 2: plast = tanh(core @ Wp[e] + bp[e]) ----
    float acc2[8][8];
    #pragma unroll
    for (int j = 0; j < 8; j++){
        const float bj = bp[me * HH + h8 + j];
        #pragma unroll
        for (int i = 0; i < 8; i++) acc2[i][j] = bj;
    }

    for (int kc2 = 0; kc2 < HH; kc2 += 32){
        __syncthreads();   // coreS writes visible (1st iter) / prev WpS consumed
        #pragma unroll
        for (int j = 0; j < 8; j++){           // Wp chunk: 32 k x 128 h
            const int q = t + 128 * j;
            const int k = q >> 5, hp = (q & 31) * 4;
            *(float4*)&WpS[k * HH + hp] = *(const float4*)(Wp + (me * HH + kc2 + k) * HH + hp);
        }
        __syncthreads();
        #pragma unroll
        for (int k0 = 0; k0 < 32; k0 += 4){
            float4 xr[8];
            #pragma unroll
            for (int i = 0; i < 8; i++) xr[i] = *(const float4*)&coreS[(r8 + i) * HH + kc2 + k0];
            #pragma unroll
            for (int kk = 0; kk < 4; kk++){
                const float4 wa = *(const float4*)&WpS[(k0 + kk) * HH + h8];
                const float4 wb = *(const float4*)&WpS[(k0 + kk) * HH + h8 + 4];
                #pragma unroll
                for (int i = 0; i < 8; i++){
                    const float xvv = (kk == 0) ? xr[i].x : (kk == 1) ? xr[i].y : (kk == 2) ? xr[i].z : xr[i].w;
                    acc2[i][0] = fmaf(xvv, wa.x, acc2[i][0]);
                    acc2[i][1] = fmaf(xvv, wa.y, acc2[i][1]);
                    acc2[i][2] = fmaf(xvv, wa.z, acc2[i][2]);
                    acc2[i][3] = fmaf(xvv, wa.w, acc2[i][3]);
                    acc2[i][4] = fmaf(xvv, wb.x, acc2[i][4]);
                    acc2[i][5] = fmaf(xvv, wb.y, acc2[i][5]);
                    acc2[i][6] = fmaf(xvv, wb.z, acc2[i][6]);
                    acc2[i][7] = fmaf(xvv, wb.w, acc2[i][7]);
                }
            }
        }
    }

    // mixed = core*(1-mv) + tanh(plast)*mv; out_e = mixed @ Wo + bo; linear split:
    float tot[8];
    #pragma unroll
    for (int i = 0; i < 8; i++){
        float s = 0.0f;
        #pragma unroll
        for (int j = 0; j < 8; j++) s = fmaf(fast_tanh(acc2[i][j]), wo[j], s);
        tot[i] = om * pc[i] + mv * s;
    }
    #pragma unroll
    for (int off = 8; off >= 1; off >>= 1){
        #pragma unroll
        for (int i = 0; i < 8; i++) tot[i] += __shfl_xor(tot[i], off, 16);
    }
    if (hg == 0){
        #pragma unroll
        for (int i = 0; i < 8; i++){
            const int s = r8 + i;
            const float w = w_s[s];
            if (w != 0.0f) atomicAdd(&out[rid_s[s]], (tot[i] + bov) * w);
        }
    }
}

extern "C" void kernel_launch(void* const* d_in, const int* in_sizes, int n_in,
                              void* d_out, int out_size, void* d_ws, size_t ws_size,
                              hipStream_t stream) {
    (void)in_sizes; (void)n_in; (void)out_size; (void)ws_size;
    const float* x   = (const float*)d_in[0];
    const float* Wg  = (const float*)d_in[1];
    const float* W1  = (const float*)d_in[2];
    const float* b1  = (const float*)d_in[3];
    const float* Wp  = (const float*)d_in[4];
    const float* bp  = (const float*)d_in[5];
    const float* ml  = (const float*)d_in[6];
    const float* Wo  = (const float*)d_in[7];
    const float* bo  = (const float*)d_in[8];
    float* out = (float*)d_out;

    // ws layout: counts (8 int, 256B-aligned block) | rowids E*B int | wgts E*B float
    char* ws = (char*)d_ws;
    int*   counts = (int*)ws;
    int*   rowids = (int*)(ws + 256);
    float* wgts   = (float*)(ws + 256 + (size_t)EE * BB * sizeof(int));

    hipMemsetAsync(counts, 0, EE * sizeof(int), stream);
    hipMemsetAsync(out, 0, BB * sizeof(float), stream);

    routing_kernel<<<BB / 4, 256, 0, stream>>>(x, Wg, counts, rowids, wgts);
    expert_kernel<<<dim3(BB / 64, EE), 128, 0, stream>>>(
        x, W1, b1, Wp, bp, ml, Wo, bo, counts, rowids, wgts, out);
}

// Round 2
// 191.055 us; speedup vs baseline: 2.8699x; 2.8699x over previous
//
#include <hip/hip_runtime.h>

#define BB 16384
#define DD 256
#define EE 8
#define HH 128

// tanh via exp2-based __expf; clamped so a=inf can't produce NaN.
__device__ __forceinline__ float fast_tanh(float v){
    v = fminf(fmaxf(v, -15.0f), 15.0f);
    const float a = __expf(2.0f * v);
    return (a - 1.0f) / (a + 1.0f);
}

// 256 threads = 4 waves; each wave computes logits for 16 rows (64 rows/block).
// Per-block LDS aggregation -> 8 global atomics per block (Guideline 12),
// instead of 2 per row (which serialized on 8 addresses: 376us -> ~8us).
__global__ __launch_bounds__(256) void routing_kernel(
    const float* __restrict__ x, const float* __restrict__ Wg,
    int* __restrict__ counts, int* __restrict__ rowids, float* __restrict__ wgts)
{
    __shared__ __align__(16) float WgT[EE][DD];   // Wg transposed: [e][d], 8 KB
    __shared__ int   le[128];     // slot s: e0 at [s], e1 at [64+s]
    __shared__ float lw[128];
    __shared__ int   loff[128];
    __shared__ int   lcount[EE];
    __shared__ int   lbase[EE];

    const int t = threadIdx.x;
    {
        // thread t loads Wg row d=t (8 floats), scatters into transposed LDS
        const float4* g = (const float4*)(Wg + t * EE);
        const float4 a = g[0], b = g[1];
        WgT[0][t] = a.x; WgT[1][t] = a.y; WgT[2][t] = a.z; WgT[3][t] = a.w;
        WgT[4][t] = b.x; WgT[5][t] = b.y; WgT[6][t] = b.z; WgT[7][t] = b.w;
    }
    if (t < EE) lcount[t] = 0;
    __syncthreads();

    const int lane = t & 63;
    const int wid  = t >> 6;
    const int rowBase = blockIdx.x * 64;

    for (int it = 0; it < 16; it++){
        const int slot = wid * 16 + it;
        const int row  = rowBase + slot;
        const float4 xv = *(const float4*)(x + row * DD + lane * 4);  // 1KB/wave, coalesced
        float p[EE];
        #pragma unroll
        for (int e = 0; e < EE; e++){
            const float4 w = *(const float4*)&WgT[e][lane * 4];
            p[e] = xv.x * w.x + xv.y * w.y + xv.z * w.z + xv.w * w.w;
        }
        #pragma unroll
        for (int off = 32; off >= 1; off >>= 1){
            #pragma unroll
            for (int e = 0; e < EE; e++) p[e] += __shfl_down(p[e], off, 64);
        }
        if (lane == 0){
            int e0 = 0; float l0 = p[0];
            #pragma unroll
            for (int e = 1; e < EE; e++){ if (p[e] > l0){ l0 = p[e]; e0 = e; } }
            int e1 = -1; float l1 = -3.0e38f;
            #pragma unroll
            for (int e = 0; e < EE; e++){ if (e != e0 && p[e] > l1){ l1 = p[e]; e1 = e; } }
            // top-2 renormalized softmax: denominators cancel; +1e-10 below fp32 eps
            const float tt  = __expf(l1 - l0);            // <= 1
            const float inv = 1.0f / (1.0f + tt);
            le[slot]      = e0;  lw[slot]      = inv;
            le[64 + slot] = e1;  lw[64 + slot] = tt * inv;
        }
    }
    __syncthreads();

    // per-block compaction: LDS histogram, one global atomic per expert
    if (t < 128) loff[t] = atomicAdd(&lcount[le[t]], 1);
    __syncthreads();
    if (t < EE) lbase[t] = atomicAdd(&counts[t], lcount[t]);
    __syncthreads();
    if (t < 128){
        const int e   = le[t];
        const int pos = lbase[e] + loff[t];
        rowids[e * BB + pos] = rowBase + (t & 63);
        wgts[e * BB + pos]   = lw[t];
    }
}

// One block = (expert me, 64 gathered rows). 128 threads; each thread owns an
// 8-row x 8-col fp32 register tile. LDS: region1 16KB (X tile / Wp chunk),
// region2 32KB (W1 tile / core), ~48.5 KB total.
__global__ __launch_bounds__(128) void expert_kernel(
    const float* __restrict__ x,
    const float* __restrict__ W1, const float* __restrict__ b1,
    const float* __restrict__ Wp, const float* __restrict__ bp,
    const float* __restrict__ mix_logit,
    const float* __restrict__ Wo, const float* __restrict__ bo,
    const int* __restrict__ counts, const int* __restrict__ rowids,
    const float* __restrict__ wgts, float* __restrict__ out)
{
    const int me    = blockIdx.y;
    const int cnt   = counts[me];
    const int start = blockIdx.x * 64;
    if (start >= cnt) return;

    __shared__ __align__(16) float reg1[64 * 64];    // 16 KB: Xs[64][64] | WpS[32][128]
    __shared__ __align__(16) float reg2[64 * 128];   // 32 KB: Ws[64][128] | coreS[64][128]
    __shared__ int   rid_s[64];
    __shared__ float w_s[64];

    float* const Xs    = reg1;   // [r][k] stride 64
    float* const WpS   = reg1;   // [k][h] stride 128 (32 rows)
    float* const Ws    = reg2;   // [k][h] stride 128
    float* const coreS = reg2;   // [r][h] stride 128

    const int t  = threadIdx.x;
    if (t < 64){
        const int idx = start + t;
        if (idx < cnt){ rid_s[t] = rowids[me * BB + idx]; w_s[t] = wgts[me * BB + idx]; }
        else          { rid_s[t] = 0;                     w_s[t] = 0.0f; }
    }
    __syncthreads();

    const int hg = t & 15;  const int h8 = hg * 8;
    const int rg = t >> 4;  const int r8 = rg * 8;

    // ---- phase 1: core = relu(x @ W1[e] + b1[e]) ----
    float acc[8][8];
    #pragma unroll
    for (int j = 0; j < 8; j++){
        const float bj = b1[me * HH + h8 + j];
        #pragma unroll
        for (int i = 0; i < 8; i++) acc[i][j] = bj;
    }

    for (int kc = 0; kc < DD; kc += 64){
        __syncthreads();   // previous tile fully consumed
        #pragma unroll
        for (int j = 0; j < 8; j++){           // X tile: 64 rows x 64 k
            const int q = t + 128 * j;
            const int r = q >> 4, kp = (q & 15) * 4;
            *(float4*)&Xs[r * 64 + kp] = *(const float4*)(x + rid_s[r] * DD + kc + kp);
        }
        #pragma unroll
        for (int j = 0; j < 16; j++){          // W1 tile: 64 k x 128 h
            const int q = t + 128 * j;
            const int k = q >> 5, hp = (q & 31) * 4;
            *(float4*)&Ws[k * HH + hp] = *(const float4*)(W1 + (me * DD + kc + k) * HH + hp);
        }
        __syncthreads();
        #pragma unroll
        for (int k0 = 0; k0 < 64; k0 += 4){
            float4 xr[8];
            #pragma unroll
            for (int i = 0; i < 8; i++) xr[i] = *(const float4*)&Xs[(r8 + i) * 64 + k0];
            #pragma unroll
            for (int kk = 0; kk < 4; kk++){
                const float4 wa = *(const float4*)&Ws[(k0 + kk) * HH + h8];
                const float4 wb = *(const float4*)&Ws[(k0 + kk) * HH + h8 + 4];
                #pragma unroll
                for (int i = 0; i < 8; i++){
                    const float xvv = (kk == 0) ? xr[i].x : (kk == 1) ? xr[i].y : (kk == 2) ? xr[i].z : xr[i].w;
                    acc[i][0] = fmaf(xvv, wa.x, acc[i][0]);
                    acc[i][1] = fmaf(xvv, wa.y, acc[i][1]);
                    acc[i][2] = fmaf(xvv, wa.z, acc[i][2]);
                    acc[i][3] = fmaf(xvv, wa.w, acc[i][3]);
                    acc[i][4] = fmaf(xvv, wb.x, acc[i][4]);
                    acc[i][5] = fmaf(xvv, wb.y, acc[i][5]);
                    acc[i][6] = fmaf(xvv, wb.z, acc[i][6]);
                    acc[i][7] = fmaf(xvv, wb.w, acc[i][7]);
                }
            }
        }
    }

    // epilogue constants
    const float mv  = 1.0f / (1.0f + __expf(-mix_logit[me]));  // sigmoid
    const float om  = 1.0f - mv;
    const float bov = bo[me];
    float wo[8];
    #pragma unroll
    for (int j = 0; j < 8; j++) wo[j] = Wo[me * HH + h8 + j];

    __syncthreads();   // all Ws/Xs reads done -> safe to overlay

    // relu, write core to LDS, and fold core's output contribution now so acc dies
    float pc[8];
    #pragma unroll
    for (int i = 0; i < 8; i++){
        float s = 0.0f;
        #pragma unroll
        for (int j = 0; j < 8; j++){
            acc[i][j] = fmaxf(acc[i][j], 0.0f);
            s = fmaf(acc[i][j], wo[j], s);
        }
        pc[i] = s;
        *(float4*)&coreS[(r8 + i) * HH + h8]     = make_float4(acc[i][0], acc[i][1], acc[i][2], acc[i][3]);
        *(float4*)&coreS[(r8 + i) * HH + h8 + 4] = make_float4(acc[i][4], acc[i][5], acc[i][6], acc[i][7]);
    }

    // ---- phase 2: plast = tanh(core @ Wp[e] + bp[e]) ----
    float acc2[8][8];
    #pragma unroll
    for (int j = 0; j < 8; j++){
        const float bj = bp[me * HH + h8 + j];
        #pragma unroll
        for (int i = 0; i < 8; i++) acc2[i][j] = bj;
    }

    for (int kc2 = 0; kc2 < HH; kc2 += 32){
        __syncthreads();   // coreS writes visible (1st iter) / prev WpS consumed
        #pragma unroll
        for (int j = 0; j < 8; j++){           // Wp chunk: 32 k x 128 h
            const int q = t + 128 * j;
            const int k = q >> 5, hp = (q & 31) * 4;
            *(float4*)&WpS[k * HH + hp] = *(const float4*)(Wp + (me * HH + kc2 + k) * HH + hp);
        }
        __syncthreads();
        #pragma unroll
        for (int k0 = 0; k0 < 32; k0 += 4){
            float4 xr[8];
            #pragma unroll
            for (int i = 0; i < 8; i++) xr[i] = *(const float4*)&coreS[(r8 + i) * HH + kc2 + k0];
            #pragma unroll
            for (int kk = 0; kk < 4; kk++){
                const float4 wa = *(const float4*)&WpS[(k0 + kk) * HH + h8];
                const float4 wb = *(const float4*)&WpS[(k0 + kk) * HH + h8 + 4];
                #pragma unroll
                for (int i = 0; i < 8; i++){
                    const float xvv = (kk == 0) ? xr[i].x : (kk == 1) ? xr[i].y : (kk == 2) ? xr[i].z : xr[i].w;
                    acc2[i][0] = fmaf(xvv, wa.x, acc2[i][0]);
                    acc2[i][1] = fmaf(xvv, wa.y, acc2[i][1]);
                    acc2[i][2] = fmaf(xvv, wa.z, acc2[i][2]);
                    acc2[i][3] = fmaf(xvv, wa.w, acc2[i][3]);
                    acc2[i][4] = fmaf(xvv, wb.x, acc2[i][4]);
                    acc2[i][5] = fmaf(xvv, wb.y, acc2[i][5]);
                    acc2[i][6] = fmaf(xvv, wb.z, acc2[i][6]);
                    acc2[i][7] = fmaf(xvv, wb.w, acc2[i][7]);
                }
            }
        }
    }

    // mixed = core*(1-mv) + tanh(plast)*mv; out_e = mixed @ Wo + bo; linear split:
    float tot[8];
    #pragma unroll
    for (int i = 0; i < 8; i++){
        float s = 0.0f;
        #pragma unroll
        for (int j = 0; j < 8; j++) s = fmaf(fast_tanh(acc2[i][j]), wo[j], s);
        tot[i] = om * pc[i] + mv * s;
    }
    #pragma unroll
    for (int off = 8; off >= 1; off >>= 1){
        #pragma unroll
        for (int i = 0; i < 8; i++) tot[i] += __shfl_xor(tot[i], off, 16);
    }
    if (hg == 0){
        #pragma unroll
        for (int i = 0; i < 8; i++){
            const int s = r8 + i;
            const float w = w_s[s];
            if (w != 0.0f) atomicAdd(&out[rid_s[s]], (tot[i] + bov) * w);
        }
    }
}

extern "C" void kernel_launch(void* const* d_in, const int* in_sizes, int n_in,
                              void* d_out, int out_size, void* d_ws, size_t ws_size,
                              hipStream_t stream) {
    (void)in_sizes; (void)n_in; (void)out_size; (void)ws_size;
    const float* x   = (const float*)d_in[0];
    const float* Wg  = (const float*)d_in[1];
    const float* W1  = (const float*)d_in[2];
    const float* b1  = (const float*)d_in[3];
    const float* Wp  = (const float*)d_in[4];
    const float* bp  = (const float*)d_in[5];
    const float* ml  = (const float*)d_in[6];
    const float* Wo  = (const float*)d_in[7];
    const float* bo  = (const float*)d_in[8];
    float* out = (float*)d_out;

    // ws layout: counts (8 int, 256B-aligned block) | rowids E*B int | wgts E*B float
    char* ws = (char*)d_ws;
    int*   counts = (int*)ws;
    int*   rowids = (int*)(ws + 256);
    float* wgts   = (float*)(ws + 256 + (size_t)EE * BB * sizeof(int));

    hipMemsetAsync(counts, 0, EE * sizeof(int), stream);
    hipMemsetAsync(out, 0, BB * sizeof(float), stream);

    routing_kernel<<<BB / 64, 256, 0, stream>>>(x, Wg, counts, rowids, wgts);
    expert_kernel<<<dim3(BB / 64, EE), 128, 0, stream>>>(
        x, W1, b1, Wp, bp, ml, Wo, bo, counts, rowids, wgts, out);
}

// Round 3
// 127.214 us; speedup vs baseline: 4.3101x; 1.5018x over previous
//
#include <hip/hip_runtime.h>

#define BB 16384
#define DD 256
#define EE 8
#define HH 128

typedef __attribute__((ext_vector_type(8))) short short8;   // 8 bf16 = 4 VGPRs
typedef __attribute__((ext_vector_type(4))) float f32x4;

// fp32 -> bf16 round-to-nearest-even (values are finite; no NaN care needed)
__device__ __forceinline__ ushort f2bf(float f){
    const unsigned u = __float_as_uint(f);
    return (ushort)((u + 0x7fffu + ((u >> 16) & 1u)) >> 16);
}
__device__ __forceinline__ float bf2f(ushort s){
    return __uint_as_float(((unsigned)s) << 16);
}
__device__ __forceinline__ float fast_tanh(float v){
    v = fminf(fmaxf(v, -15.0f), 15.0f);
    const float a = __expf(2.0f * v);
    return (a - 1.0f) / (a + 1.0f);
}

// ---------------------------------------------------------------------------
// Prepass: W1 [e][k=256][h=128] fp32  ->  W1t [e][h][k] bf16
//          Wp [e][k=128][h=128] fp32  ->  Wpt [e][h][k] bf16
// so MFMA B-fragments are contiguous 16B reads. 96 blocks, ~0.5 MB out.
__global__ __launch_bounds__(256) void transpose_kernel(
    const float* __restrict__ W1, const float* __restrict__ Wp,
    ushort* __restrict__ W1t, ushort* __restrict__ Wpt)
{
    __shared__ float tile[64 * 68];   // 64x64 fp32 tile, pad 68 vs bank conflicts
    int b = blockIdx.x;
    const float* src; ushort* dst; int K;
    int k0, h0;
    if (b < 64){                                    // W1: 8e x 4kt x 2ht
        const int e = b >> 3, kt = (b >> 1) & 3, ht = b & 1;
        src = W1 + (size_t)e * DD * HH;  dst = W1t + (size_t)e * HH * DD;
        K = DD; k0 = kt * 64; h0 = ht * 64;
    } else {                                        // Wp: 8e x 2kt x 2ht
        b -= 64;
        const int e = b >> 2, kt = (b >> 1) & 1, ht = b & 1;
        src = Wp + (size_t)e * HH * HH;  dst = Wpt + (size_t)e * HH * HH;
        K = HH; k0 = kt * 64; h0 = ht * 64;
    }
    const int t = threadIdx.x;
    #pragma unroll
    for (int j = 0; j < 4; j++){
        const int idx = t + 256 * j;               // 1024 float4 = 64x64
        const int kk = idx >> 4, hh = (idx & 15) * 4;
        const float4 v = *(const float4*)(src + (size_t)(k0 + kk) * HH + h0 + hh);
        *(float4*)&tile[kk * 68 + hh] = v;
    }
    __syncthreads();
    #pragma unroll
    for (int j = 0; j < 4; j++){
        const int idx = t + 256 * j;
        const int hh = idx >> 4, kk = (idx & 15) * 4;
        ushort4 o;
        o.x = f2bf(tile[(kk + 0) * 68 + hh]);
        o.y = f2bf(tile[(kk + 1) * 68 + hh]);
        o.z = f2bf(tile[(kk + 2) * 68 + hh]);
        o.w = f2bf(tile[(kk + 3) * 68 + hh]);
        *(ushort4*)&dst[(size_t)(h0 + hh) * K + k0 + kk] = o;
    }
}

// ---------------------------------------------------------------------------
// Routing: unchanged from round 2 (block-aggregated atomics).
__global__ __launch_bounds__(256) void routing_kernel(
    const float* __restrict__ x, const float* __restrict__ Wg,
    int* __restrict__ counts, int* __restrict__ rowids, float* __restrict__ wgts)
{
    __shared__ __align__(16) float WgT[EE][DD];
    __shared__ int   le[128];
    __shared__ float lw[128];
    __shared__ int   loff[128];
    __shared__ int   lcount[EE];
    __shared__ int   lbase[EE];

    const int t = threadIdx.x;
    {
        const float4* g = (const float4*)(Wg + t * EE);
        const float4 a = g[0], b = g[1];
        WgT[0][t] = a.x; WgT[1][t] = a.y; WgT[2][t] = a.z; WgT[3][t] = a.w;
        WgT[4][t] = b.x; WgT[5][t] = b.y; WgT[6][t] = b.z; WgT[7][t] = b.w;
    }
    if (t < EE) lcount[t] = 0;
    __syncthreads();

    const int lane = t & 63;
    const int wid  = t >> 6;
    const int rowBase = blockIdx.x * 64;

    for (int it = 0; it < 16; it++){
        const int slot = wid * 16 + it;
        const int row  = rowBase + slot;
        const float4 xv = *(const float4*)(x + row * DD + lane * 4);
        float p[EE];
        #pragma unroll
        for (int e = 0; e < EE; e++){
            const float4 w = *(const float4*)&WgT[e][lane * 4];
            p[e] = xv.x * w.x + xv.y * w.y + xv.z * w.z + xv.w * w.w;
        }
        #pragma unroll
        for (int off = 32; off >= 1; off >>= 1){
            #pragma unroll
            for (int e = 0; e < EE; e++) p[e] += __shfl_down(p[e], off, 64);
        }
        if (lane == 0){
            int e0 = 0; float l0 = p[0];
            #pragma unroll
            for (int e = 1; e < EE; e++){ if (p[e] > l0){ l0 = p[e]; e0 = e; } }
            int e1 = -1; float l1 = -3.0e38f;
            #pragma unroll
            for (int e = 0; e < EE; e++){ if (e != e0 && p[e] > l1){ l1 = p[e]; e1 = e; } }
            const float tt  = __expf(l1 - l0);
            const float inv = 1.0f / (1.0f + tt);
            le[slot]      = e0;  lw[slot]      = inv;
            le[64 + slot] = e1;  lw[64 + slot] = tt * inv;
        }
    }
    __syncthreads();
    if (t < 128) loff[t] = atomicAdd(&lcount[le[t]], 1);
    __syncthreads();
    if (t < EE) lbase[t] = atomicAdd(&counts[t], lcount[t]);
    __syncthreads();
    if (t < 128){
        const int e   = le[t];
        const int pos = lbase[e] + loff[t];
        rowids[e * BB + pos] = rowBase + (t & 63);
        wgts[e * BB + pos]   = lw[t];
    }
}

// ---------------------------------------------------------------------------
// Expert kernel, MFMA bf16. Block = 256 threads (4 waves), 64 gathered rows,
// output tile 64 x 128. Wave w: rows 32*(w>>1), cols 64*(w&1) -> 2x4 tiles of
// 16x16. A from LDS (bf16, pad +8), B direct from transposed global (L2-hot).
// mfma_f32_16x16x32_bf16 layouts (HW-verified): A[m=lane&15][k=quad*8+j],
// B[k=quad*8+j][n=lane&15], C col=lane&15 row=quad*4+reg.
#define XS_S 264   // 256 + 8 bf16 pad
#define CS_S 136   // 128 + 8 bf16 pad

__global__ __launch_bounds__(256, 2) void expert_kernel(
    const float* __restrict__ x,
    const ushort* __restrict__ W1t, const float* __restrict__ b1,
    const ushort* __restrict__ Wpt, const float* __restrict__ bp,
    const float* __restrict__ mix_logit,
    const float* __restrict__ Wo, const float* __restrict__ bo,
    const int* __restrict__ counts, const int* __restrict__ rowids,
    const float* __restrict__ wgts, float* __restrict__ out)
{
    const int me    = blockIdx.y;
    const int cnt   = counts[me];
    const int start = blockIdx.x * 64;
    if (start >= cnt) return;

    __shared__ ushort Xs[64 * XS_S];     // 33.8 KB
    __shared__ ushort coreS[64 * CS_S];  // 17.4 KB
    __shared__ int   rid_s[64];
    __shared__ float w_s[64];

    const int t = threadIdx.x;
    if (t < 64){
        const int idx = start + t;
        if (idx < cnt){ rid_s[t] = rowids[me * BB + idx]; w_s[t] = wgts[me * BB + idx]; }
        else          { rid_s[t] = 0;                     w_s[t] = 0.0f; }
    }
    __syncthreads();

    // stage X rows (fp32 global -> bf16 LDS), coalesced 1KB/wave
    #pragma unroll
    for (int j = 0; j < 16; j++){
        const int idx = t + 256 * j;          // 4096 float4 = 64 x 256
        const int r  = idx >> 6;
        const int kq = (idx & 63) << 2;
        const float4 v = *(const float4*)(x + (size_t)rid_s[r] * DD + kq);
        ushort4 bv;
        bv.x = f2bf(v.x); bv.y = f2bf(v.y); bv.z = f2bf(v.z); bv.w = f2bf(v.w);
        *(ushort4*)&Xs[r * XS_S + kq] = bv;
    }
    __syncthreads();

    const int lane = t & 63;
    const int w    = t >> 6;
    const int m16  = lane & 15;
    const int q    = lane >> 4;
    const int r0   = 32 * (w >> 1);
    const int c0   = 64 * (w & 1);

    // ---- GEMM1: core_pre = X @ W1 + b1 ----
    f32x4 acc[2][4];
    #pragma unroll
    for (int ct = 0; ct < 4; ct++){
        const float bj = b1[me * HH + c0 + ct * 16 + m16];
        #pragma unroll
        for (int rt = 0; rt < 2; rt++) acc[rt][ct] = (f32x4){bj, bj, bj, bj};
    }
    const ushort* W1te = W1t + (size_t)me * HH * DD;
    #pragma unroll
    for (int ks = 0; ks < 8; ks++){
        const int k0 = ks * 32;
        short8 af[2], bf[4];
        #pragma unroll
        for (int rt = 0; rt < 2; rt++)
            af[rt] = *(const short8*)&Xs[(r0 + rt * 16 + m16) * XS_S + k0 + q * 8];
        #pragma unroll
        for (int ct = 0; ct < 4; ct++)
            bf[ct] = *(const short8*)&W1te[(size_t)(c0 + ct * 16 + m16) * DD + k0 + q * 8];
        #pragma unroll
        for (int rt = 0; rt < 2; rt++)
            #pragma unroll
            for (int ct = 0; ct < 4; ct++)
                acc[rt][ct] = __builtin_amdgcn_mfma_f32_16x16x32_bf16(af[rt], bf[ct], acc[rt][ct], 0, 0, 0);
    }

    // relu -> bf16 core into LDS (A-operand source for GEMM2 + epilogue reuse)
    #pragma unroll
    for (int rt = 0; rt < 2; rt++)
        #pragma unroll
        for (int ct = 0; ct < 4; ct++)
            #pragma unroll
            for (int j = 0; j < 4; j++){
                const int row = r0 + rt * 16 + q * 4 + j;
                const int col = c0 + ct * 16 + m16;
                coreS[row * CS_S + col] = f2bf(fmaxf(acc[rt][ct][j], 0.0f));
            }
    __syncthreads();

    // ---- GEMM2: plast_pre = core @ Wp + bp ----
    #pragma unroll
    for (int ct = 0; ct < 4; ct++){
        const float bj = bp[me * HH + c0 + ct * 16 + m16];
        #pragma unroll
        for (int rt = 0; rt < 2; rt++) acc[rt][ct] = (f32x4){bj, bj, bj, bj};
    }
    const ushort* Wpte = Wpt + (size_t)me * HH * HH;
    #pragma unroll
    for (int ks = 0; ks < 4; ks++){
        const int k0 = ks * 32;
        short8 af[2], bf[4];
        #pragma unroll
        for (int rt = 0; rt < 2; rt++)
            af[rt] = *(const short8*)&coreS[(r0 + rt * 16 + m16) * CS_S + k0 + q * 8];
        #pragma unroll
        for (int ct = 0; ct < 4; ct++)
            bf[ct] = *(const short8*)&Wpte[(size_t)(c0 + ct * 16 + m16) * HH + k0 + q * 8];
        #pragma unroll
        for (int rt = 0; rt < 2; rt++)
            #pragma unroll
            for (int ct = 0; ct < 4; ct++)
                acc[rt][ct] = __builtin_amdgcn_mfma_f32_16x16x32_bf16(af[rt], bf[ct], acc[rt][ct], 0, 0, 0);
    }

    // ---- epilogue: out_row = sum_h [core*(1-m) + m*tanh(plast)] * Wo + bo ----
    const float mv  = 1.0f / (1.0f + __expf(-mix_logit[me]));
    const float om  = 1.0f - mv;
    const float bov = bo[me];
    float wo[4];
    #pragma unroll
    for (int ct = 0; ct < 4; ct++) wo[ct] = Wo[me * HH + c0 + ct * 16 + m16];

    float red[2][4];
    #pragma unroll
    for (int rt = 0; rt < 2; rt++)
        #pragma unroll
        for (int j = 0; j < 4; j++){
            float s = 0.0f;
            const int row = r0 + rt * 16 + q * 4 + j;
            #pragma unroll
            for (int ct = 0; ct < 4; ct++){
                const int col = c0 + ct * 16 + m16;
                const float pl = fast_tanh(acc[rt][ct][j]);
                const float cv = bf2f(coreS[row * CS_S + col]);
                s = fmaf(om * cv + mv * pl, wo[ct], s);
            }
            red[rt][j] = s;
        }
    #pragma unroll
    for (int off = 8; off >= 1; off >>= 1)
        #pragma unroll
        for (int rt = 0; rt < 2; rt++)
            #pragma unroll
            for (int j = 0; j < 4; j++)
                red[rt][j] += __shfl_xor(red[rt][j], off, 64);   // reduce over m16

    if (m16 == 0){
        const float bb = (c0 == 0) ? bov : 0.0f;   // add bias from one col-half only
        #pragma unroll
        for (int rt = 0; rt < 2; rt++)
            #pragma unroll
            for (int j = 0; j < 4; j++){
                const int row = r0 + rt * 16 + q * 4 + j;
                const float ww = w_s[row];
                if (ww != 0.0f) atomicAdd(&out[rid_s[row]], (red[rt][j] + bb) * ww);
            }
    }
}

extern "C" void kernel_launch(void* const* d_in, const int* in_sizes, int n_in,
                              void* d_out, int out_size, void* d_ws, size_t ws_size,
                              hipStream_t stream) {
    (void)in_sizes; (void)n_in; (void)out_size; (void)ws_size;
    const float* x   = (const float*)d_in[0];
    const float* Wg  = (const float*)d_in[1];
    const float* W1  = (const float*)d_in[2];
    const float* b1  = (const float*)d_in[3];
    const float* Wp  = (const float*)d_in[4];
    const float* bp  = (const float*)d_in[5];
    const float* ml  = (const float*)d_in[6];
    const float* Wo  = (const float*)d_in[7];
    const float* bo  = (const float*)d_in[8];
    float* out = (float*)d_out;

    // ws layout (16B-aligned blocks):
    //   counts 256B | rowids E*B*4 | wgts E*B*4 | W1t E*H*D*2 | Wpt E*H*H*2
    char* ws = (char*)d_ws;
    int*    counts = (int*)ws;
    int*    rowids = (int*)(ws + 256);
    float*  wgts   = (float*)(ws + 256 + (size_t)EE * BB * 4);
    ushort* W1t    = (ushort*)(ws + 256 + 2 * (size_t)EE * BB * 4);
    ushort* Wpt    = W1t + (size_t)EE * HH * DD;

    hipMemsetAsync(counts, 0, EE * sizeof(int), stream);
    hipMemsetAsync(out, 0, BB * sizeof(float), stream);

    transpose_kernel<<<96, 256, 0, stream>>>(W1, Wp, W1t, Wpt);
    routing_kernel<<<BB / 64, 256, 0, stream>>>(x, Wg, counts, rowids, wgts);
    expert_kernel<<<dim3(BB / 64, EE), 256, 0, stream>>>(
        x, W1t, b1, Wpt, bp, ml, Wo, bo, counts, rowids, wgts, out);
}

// Round 4
// 119.438 us; speedup vs baseline: 4.5907x; 1.0651x over previous
//
#include <hip/hip_runtime.h>

#define BB 16384
#define DD 256
#define EE 8
#define HH 128

typedef __attribute__((ext_vector_type(8))) short short8;   // 8 bf16 = 4 VGPRs
typedef __attribute__((ext_vector_type(4))) float f32x4;

// fp32 -> bf16 round-to-nearest-even (values are finite; no NaN care needed)
__device__ __forceinline__ ushort f2bf(float f){
    const unsigned u = __float_as_uint(f);
    return (ushort)((u + 0x7fffu + ((u >> 16) & 1u)) >> 16);
}
__device__ __forceinline__ float bf2f(ushort s){
    return __uint_as_float(((unsigned)s) << 16);
}
__device__ __forceinline__ float fast_tanh(float v){
    v = fminf(fmaxf(v, -15.0f), 15.0f);
    const float a = __expf(2.0f * v);
    return (a - 1.0f) / (a + 1.0f);
}

// ---------------------------------------------------------------------------
// Prepass: W1 [e][k=256][h=128] fp32 -> W1t [e][h][k] bf16; Wp likewise.
// Also zeroes the routing counts (block 0) -- stream-ordered before routing,
// which removes one hipMemsetAsync dispatch.
__global__ __launch_bounds__(256) void transpose_kernel(
    const float* __restrict__ W1, const float* __restrict__ Wp,
    ushort* __restrict__ W1t, ushort* __restrict__ Wpt, int* __restrict__ counts)
{
    __shared__ float tile[64 * 68];   // 64x64 fp32 tile, pad 68 vs bank conflicts
    int b = blockIdx.x;
    const int t = threadIdx.x;
    if (b == 0 && t < EE) counts[t] = 0;
    const float* src; ushort* dst; int K;
    int k0, h0;
    if (b < 64){                                    // W1: 8e x 4kt x 2ht
        const int e = b >> 3, kt = (b >> 1) & 3, ht = b & 1;
        src = W1 + (size_t)e * DD * HH;  dst = W1t + (size_t)e * HH * DD;
        K = DD; k0 = kt * 64; h0 = ht * 64;
    } else {                                        // Wp: 8e x 2kt x 2ht
        b -= 64;
        const int e = b >> 2, kt = (b >> 1) & 1, ht = b & 1;
        src = Wp + (size_t)e * HH * HH;  dst = Wpt + (size_t)e * HH * HH;
        K = HH; k0 = kt * 64; h0 = ht * 64;
    }
    #pragma unroll
    for (int j = 0; j < 4; j++){
        const int idx = t + 256 * j;               // 1024 float4 = 64x64
        const int kk = idx >> 4, hh = (idx & 15) * 4;
        const float4 v = *(const float4*)(src + (size_t)(k0 + kk) * HH + h0 + hh);
        *(float4*)&tile[kk * 68 + hh] = v;
    }
    __syncthreads();
    #pragma unroll
    for (int j = 0; j < 4; j++){
        const int idx = t + 256 * j;
        const int hh = idx >> 4, kk = (idx & 15) * 4;
        ushort4 o;
        o.x = f2bf(tile[(kk + 0) * 68 + hh]);
        o.y = f2bf(tile[(kk + 1) * 68 + hh]);
        o.z = f2bf(tile[(kk + 2) * 68 + hh]);
        o.w = f2bf(tile[(kk + 3) * 68 + hh]);
        *(ushort4*)&dst[(size_t)(h0 + hh) * K + k0 + kk] = o;
    }
}

// ---------------------------------------------------------------------------
// Routing: 32 rows/block (512 blocks -> 2 blocks/CU, halves the serial
// per-wave row chain vs 64 rows/block). Block-aggregated global atomics.
// Also zeroes this block's out[] rows (stream-ordered before expert kernel),
// removing the second hipMemsetAsync dispatch. Stays fp32: bf16 logits would
// flip near-tie top-2 picks (~2% of rows within bf16 eps -> O(0.3) errors).
__global__ __launch_bounds__(256) void routing_kernel(
    const float* __restrict__ x, const float* __restrict__ Wg,
    int* __restrict__ counts, int* __restrict__ rowids, float* __restrict__ wgts,
    float* __restrict__ out)
{
    __shared__ __align__(16) float WgT[EE][DD];
    __shared__ int   le[64];      // slot s: e0 at [s], e1 at [32+s]
    __shared__ float lw[64];
    __shared__ int   loff[64];
    __shared__ int   lcount[EE];
    __shared__ int   lbase[EE];

    const int t = threadIdx.x;
    const int rowBase = blockIdx.x * 32;
    if (t < 32) out[rowBase + t] = 0.0f;
    {
        const float4* g = (const float4*)(Wg + t * EE);
        const float4 a = g[0], b = g[1];
        WgT[0][t] = a.x; WgT[1][t] = a.y; WgT[2][t] = a.z; WgT[3][t] = a.w;
        WgT[4][t] = b.x; WgT[5][t] = b.y; WgT[6][t] = b.z; WgT[7][t] = b.w;
    }
    if (t < EE) lcount[t] = 0;
    __syncthreads();

    const int lane = t & 63;
    const int wid  = t >> 6;

    for (int it = 0; it < 8; it++){
        const int slot = wid * 8 + it;
        const int row  = rowBase + slot;
        const float4 xv = *(const float4*)(x + row * DD + lane * 4);
        float p[EE];
        #pragma unroll
        for (int e = 0; e < EE; e++){
            const float4 w = *(const float4*)&WgT[e][lane * 4];
            p[e] = xv.x * w.x + xv.y * w.y + xv.z * w.z + xv.w * w.w;
        }
        #pragma unroll
        for (int off = 32; off >= 1; off >>= 1){
            #pragma unroll
            for (int e = 0; e < EE; e++) p[e] += __shfl_down(p[e], off, 64);
        }
        if (lane == 0){
            int e0 = 0; float l0 = p[0];
            #pragma unroll
            for (int e = 1; e < EE; e++){ if (p[e] > l0){ l0 = p[e]; e0 = e; } }
            int e1 = -1; float l1 = -3.0e38f;
            #pragma unroll
            for (int e = 0; e < EE; e++){ if (e != e0 && p[e] > l1){ l1 = p[e]; e1 = e; } }
            const float tt  = __expf(l1 - l0);            // <= 1
            const float inv = 1.0f / (1.0f + tt);
            le[slot]      = e0;  lw[slot]      = inv;
            le[32 + slot] = e1;  lw[32 + slot] = tt * inv;
        }
    }
    __syncthreads();
    if (t < 64) loff[t] = atomicAdd(&lcount[le[t]], 1);
    __syncthreads();
    if (t < EE) lbase[t] = atomicAdd(&counts[t], lcount[t]);
    __syncthreads();
    if (t < 64){
        const int e   = le[t];
        const int pos = lbase[e] + loff[t];
        rowids[e * BB + pos] = rowBase + (t & 31);
        wgts[e * BB + pos]   = lw[t];
    }
}

// ---------------------------------------------------------------------------
// Expert kernel, MFMA bf16 (unchanged from round 3). Block = 4 waves, 64 rows,
// 64x128 output tile; wave w: rows 32*(w>>1), cols 64*(w&1), 2x4 16x16 tiles.
// mfma_f32_16x16x32_bf16: A[m=lane&15][k=quad*8+j], B[k][n=lane&15],
// C col=lane&15 row=quad*4+reg.
#define XS_S 264   // 256 + 8 bf16 pad
#define CS_S 136   // 128 + 8 bf16 pad

__global__ __launch_bounds__(256, 2) void expert_kernel(
    const float* __restrict__ x,
    const ushort* __restrict__ W1t, const float* __restrict__ b1,
    const ushort* __restrict__ Wpt, const float* __restrict__ bp,
    const float* __restrict__ mix_logit,
    const float* __restrict__ Wo, const float* __restrict__ bo,
    const int* __restrict__ counts, const int* __restrict__ rowids,
    const float* __restrict__ wgts, float* __restrict__ out)
{
    const int me    = blockIdx.y;
    const int cnt   = counts[me];
    const int start = blockIdx.x * 64;
    if (start >= cnt) return;

    __shared__ ushort Xs[64 * XS_S];     // 33.8 KB
    __shared__ ushort coreS[64 * CS_S];  // 17.4 KB
    __shared__ int   rid_s[64];
    __shared__ float w_s[64];

    const int t = threadIdx.x;
    if (t < 64){
        const int idx = start + t;
        if (idx < cnt){ rid_s[t] = rowids[me * BB + idx]; w_s[t] = wgts[me * BB + idx]; }
        else          { rid_s[t] = 0;                     w_s[t] = 0.0f; }
    }
    __syncthreads();

    #pragma unroll
    for (int j = 0; j < 16; j++){
        const int idx = t + 256 * j;          // 4096 float4 = 64 x 256
        const int r  = idx >> 6;
        const int kq = (idx & 63) << 2;
        const float4 v = *(const float4*)(x + (size_t)rid_s[r] * DD + kq);
        ushort4 bv;
        bv.x = f2bf(v.x); bv.y = f2bf(v.y); bv.z = f2bf(v.z); bv.w = f2bf(v.w);
        *(ushort4*)&Xs[r * XS_S + kq] = bv;
    }
    __syncthreads();

    const int lane = t & 63;
    const int w    = t >> 6;
    const int m16  = lane & 15;
    const int q    = lane >> 4;
    const int r0   = 32 * (w >> 1);
    const int c0   = 64 * (w & 1);

    // ---- GEMM1: core_pre = X @ W1 + b1 ----
    f32x4 acc[2][4];
    #pragma unroll
    for (int ct = 0; ct < 4; ct++){
        const float bj = b1[me * HH + c0 + ct * 16 + m16];
        #pragma unroll
        for (int rt = 0; rt < 2; rt++) acc[rt][ct] = (f32x4){bj, bj, bj, bj};
    }
    const ushort* W1te = W1t + (size_t)me * HH * DD;
    #pragma unroll
    for (int ks = 0; ks < 8; ks++){
        const int k0 = ks * 32;
        short8 af[2], bf[4];
        #pragma unroll
        for (int rt = 0; rt < 2; rt++)
            af[rt] = *(const short8*)&Xs[(r0 + rt * 16 + m16) * XS_S + k0 + q * 8];
        #pragma unroll
        for (int ct = 0; ct < 4; ct++)
            bf[ct] = *(const short8*)&W1te[(size_t)(c0 + ct * 16 + m16) * DD + k0 + q * 8];
        #pragma unroll
        for (int rt = 0; rt < 2; rt++)
            #pragma unroll
            for (int ct = 0; ct < 4; ct++)
                acc[rt][ct] = __builtin_amdgcn_mfma_f32_16x16x32_bf16(af[rt], bf[ct], acc[rt][ct], 0, 0, 0);
    }

    // relu -> bf16 core into LDS (A-operand source for GEMM2 + epilogue reuse)
    #pragma unroll
    for (int rt = 0; rt < 2; rt++)
        #pragma unroll
        for (int ct = 0; ct < 4; ct++)
            #pragma unroll
            for (int j = 0; j < 4; j++){
                const int row = r0 + rt * 16 + q * 4 + j;
                const int col = c0 + ct * 16 + m16;
                coreS[row * CS_S + col] = f2bf(fmaxf(acc[rt][ct][j], 0.0f));
            }
    __syncthreads();

    // ---- GEMM2: plast_pre = core @ Wp + bp ----
    #pragma unroll
    for (int ct = 0; ct < 4; ct++){
        const float bj = bp[me * HH + c0 + ct * 16 + m16];
        #pragma unroll
        for (int rt = 0; rt < 2; rt++) acc[rt][ct] = (f32x4){bj, bj, bj, bj};
    }
    const ushort* Wpte = Wpt + (size_t)me * HH * HH;
    #pragma unroll
    for (int ks = 0; ks < 4; ks++){
        const int k0 = ks * 32;
        short8 af[2], bf[4];
        #pragma unroll
        for (int rt = 0; rt < 2; rt++)
            af[rt] = *(const short8*)&coreS[(r0 + rt * 16 + m16) * CS_S + k0 + q * 8];
        #pragma unroll
        for (int ct = 0; ct < 4; ct++)
            bf[ct] = *(const short8*)&Wpte[(size_t)(c0 + ct * 16 + m16) * HH + k0 + q * 8];
        #pragma unroll
        for (int rt = 0; rt < 2; rt++)
            #pragma unroll
            for (int ct = 0; ct < 4; ct++)
                acc[rt][ct] = __builtin_amdgcn_mfma_f32_16x16x32_bf16(af[rt], bf[ct], acc[rt][ct], 0, 0, 0);
    }

    // ---- epilogue: out_row = sum_h [core*(1-m) + m*tanh(plast)] * Wo + bo ----
    const float mv  = 1.0f / (1.0f + __expf(-mix_logit[me]));
    const float om  = 1.0f - mv;
    const float bov = bo[me];
    float wo[4];
    #pragma unroll
    for (int ct = 0; ct < 4; ct++) wo[ct] = Wo[me * HH + c0 + ct * 16 + m16];

    float red[2][4];
    #pragma unroll
    for (int rt = 0; rt < 2; rt++)
        #pragma unroll
        for (int j = 0; j < 4; j++){
            float s = 0.0f;
            const int row = r0 + rt * 16 + q * 4 + j;
            #pragma unroll
            for (int ct = 0; ct < 4; ct++){
                const int col = c0 + ct * 16 + m16;
                const float pl = fast_tanh(acc[rt][ct][j]);
                const float cv = bf2f(coreS[row * CS_S + col]);
                s = fmaf(om * cv + mv * pl, wo[ct], s);
            }
            red[rt][j] = s;
        }
    #pragma unroll
    for (int off = 8; off >= 1; off >>= 1)
        #pragma unroll
        for (int rt = 0; rt < 2; rt++)
            #pragma unroll
            for (int j = 0; j < 4; j++)
                red[rt][j] += __shfl_xor(red[rt][j], off, 64);   // reduce over m16

    if (m16 == 0){
        const float bb = (c0 == 0) ? bov : 0.0f;   // bias from one col-half only
        #pragma unroll
        for (int rt = 0; rt < 2; rt++)
            #pragma unroll
            for (int j = 0; j < 4; j++){
                const int row = r0 + rt * 16 + q * 4 + j;
                const float ww = w_s[row];
                if (ww != 0.0f) atomicAdd(&out[rid_s[row]], (red[rt][j] + bb) * ww);
            }
    }
}

extern "C" void kernel_launch(void* const* d_in, const int* in_sizes, int n_in,
                              void* d_out, int out_size, void* d_ws, size_t ws_size,
                              hipStream_t stream) {
    (void)in_sizes; (void)n_in; (void)out_size; (void)ws_size;
    const float* x   = (const float*)d_in[0];
    const float* Wg  = (const float*)d_in[1];
    const float* W1  = (const float*)d_in[2];
    const float* b1  = (const float*)d_in[3];
    const float* Wp  = (const float*)d_in[4];
    const float* bp  = (const float*)d_in[5];
    const float* ml  = (const float*)d_in[6];
    const float* Wo  = (const float*)d_in[7];
    const float* bo  = (const float*)d_in[8];
    float* out = (float*)d_out;

    // ws layout (16B-aligned blocks):
    //   counts 256B | rowids E*B*4 | wgts E*B*4 | W1t E*H*D*2 | Wpt E*H*H*2
    char* ws = (char*)d_ws;
    int*    counts = (int*)ws;
    int*    rowids = (int*)(ws + 256);
    float*  wgts   = (float*)(ws + 256 + (size_t)EE * BB * 4);
    ushort* W1t    = (ushort*)(ws + 256 + 2 * (size_t)EE * BB * 4);
    ushort* Wpt    = W1t + (size_t)EE * HH * DD;

    // 3 dispatches, no memsets: transpose zeroes counts (block 0), routing
    // zeroes out[] (its own rows) -- both stream-ordered before their readers.
    transpose_kernel<<<96, 256, 0, stream>>>(W1, Wp, W1t, Wpt, counts);
    routing_kernel<<<BB / 32, 256, 0, stream>>>(x, Wg, counts, rowids, wgts, out);
    expert_kernel<<<dim3(BB / 64, EE), 256, 0, stream>>>(
        x, W1t, b1, Wpt, bp, ml, Wo, bo, counts, rowids, wgts, out);
}